// Round 5
// baseline (181.229 us; speedup 1.0000x reference)
//
#include <hip/hip_runtime.h>

// filtered_lrelu: 2x FIR up (12 taps) -> lrelu(0.01) -> 2x FIR down (12 taps)
// x: [8,128,130,130] f32, filters: 12 f32, out: [8,128,128,128] f32.
//
// Gain: raw up filters; fd = 2*down reversed, applied on both axes => x4 total
// (exact: lrelu(s*z) = s*lrelu(z) for s>0; downsampling linear).
//
// This round: packed-fp32 (v_pk_fma_f32) formulation. Stage B processes a
// COLUMN PAIR per thread as float2 (scalar coefficient splats, ds_read_b64
// data) -> half the issue slots per column, single 32-row segment kills the
// duplicated 5-iter prime. Stage A packs (u0,u1)/(u2,u3) with coefficient
// pairs. If ISel fails to pack, this lowers to the same scalar count as R4.
//
// Tile 32x32 outputs/block, 256 threads, LDS 22496 B -> 7 blocks/CU.

#define TOX 32
#define TOY 32
#define XST 44          // xs row stride (floats)
#define UST 76          // u and w row stride (floats)
#define U_ROWS 42
#define XW_FLOATS (32 * UST)   // 2432: max(xs 42*44=1848, w 32*76=2432)

static __device__ __forceinline__ float2 f2(float a, float b) { return make_float2(a, b); }
static __device__ __forceinline__ float2 pk_fma(float2 a, float2 b, float2 c) {
    return make_float2(__builtin_fmaf(a.x, b.x, c.x), __builtin_fmaf(a.y, b.y, c.y));
}
static __device__ __forceinline__ float2 pk_fma_s(float s, float2 b, float2 c) {
    return make_float2(__builtin_fmaf(s, b.x, c.x), __builtin_fmaf(s, b.y, c.y));
}
static __device__ __forceinline__ float2 pk_mul_s(float s, float2 b) {
    return make_float2(s * b.x, s * b.y);
}
static __device__ __forceinline__ float2 pk_lrelu(float2 z) {
    return make_float2(fmaxf(z.x, 0.01f * z.x), fmaxf(z.y, 0.01f * z.y));
}

__global__ __launch_bounds__(256, 7)
void flrelu_fused_kernel(const float* __restrict__ x,
                         const float* __restrict__ upf,
                         const float* __restrict__ downf,
                         float* __restrict__ out) {
    __shared__ __align__(16) float u_s[U_ROWS * UST];   // 12768 B
    __shared__ __align__(16) float xw_s[XW_FLOATS];     //  9728 B (xs, then w)

    const int tid = threadIdx.x;
    const int ch  = blockIdx.z;
    const int ox0 = blockIdx.x * TOX;
    const int oy0 = blockIdx.y * TOY;

    // Uniform filter loads. fu raw; fd = 2*down reversed (gain split per axis).
    float fu[12], fd[12];
#pragma unroll
    for (int t = 0; t < 12; ++t) fu[t] = upf[t];
#pragma unroll
    for (int t = 0; t < 12; ++t) fd[t] = 2.0f * downf[11 - t];

    // ---- stage 0: global -> xs (zero halo), 42 rows x 22 float2 ----
    {
        const float* __restrict__ xc = x + (size_t)ch * (130 * 130);
        float* xs = xw_s;
        for (int idx = tid; idx < U_ROWS * 22; idx += 256) {   // 924 tasks
            const int r  = idx / 22;
            const int c2 = idx - r * 22;
            const int gr = oy0 - 4 + r;
            const int gc = ox0 - 4 + 2 * c2;
            float2 v = make_float2(0.f, 0.f);
            if ((unsigned)gr < 130u && (unsigned)gc <= 128u)
                v = *(const float2*)(xc + gr * 130 + gc);
            *(float2*)(xs + r * XST + 2 * c2) = v;
        }
    }
    __syncthreads();

    // ---- stage A: horizontal up-conv: xs -> u[42][76], packed pairs ----
    // (u0,u1) = sum_j cf[j] * splat(s_{5-j});  (u2,u3) same with s_{6-j}.
    {
        const float2 cf0 = f2(fu[0], fu[1]),  cf1 = f2(fu[2], fu[3]),
                     cf2 = f2(fu[4], fu[5]),  cf3 = f2(fu[6], fu[7]),
                     cf4 = f2(fu[8], fu[9]),  cf5 = f2(fu[10], fu[11]);
        const float* xs = xw_s;
        const int h0 = tid / 19;         // 0..13 (tid<247 active)
        const int g  = tid - 19 * h0;
        if (tid < 247) {
#pragma unroll
            for (int k = 0; k < 4; ++k) {
                const int h = h0 + 13 * k;
                if (h < U_ROWS) {
                    const float* xr = xs + h * XST + 2 * g;
                    float2 s01 = *(const float2*)(xr);
                    float2 s23 = *(const float2*)(xr + 2);
                    float2 s45 = *(const float2*)(xr + 4);
                    float  s6  = xr[6];
                    float2 p01 = pk_fma(cf1, f2(s45.x, s45.x),
                                 pk_fma(cf2, f2(s23.y, s23.y),
                                 pk_fma(cf3, f2(s23.x, s23.x),
                                 pk_fma(cf4, f2(s01.y, s01.y),
                                 pk_fma(cf5, f2(s01.x, s01.x),
                                        pk_mul_s(s45.y, cf0))))));
                    float2 p23 = pk_fma(cf1, f2(s45.y, s45.y),
                                 pk_fma(cf2, f2(s45.x, s45.x),
                                 pk_fma(cf3, f2(s23.y, s23.y),
                                 pk_fma(cf4, f2(s23.x, s23.x),
                                 pk_fma(cf5, f2(s01.y, s01.y),
                                        pk_mul_s(s6, cf0))))));
                    *(float4*)(u_s + h * UST + 4 * g) =
                        make_float4(p01.x, p01.y, p23.x, p23.y);
                }
            }
        }
    }
    __syncthreads();

    // ---- stage B: vert up + lrelu + vert down, fused sliding window ----
    // 38 tasks, one COLUMN PAIR each, all 32 output rows per task.
    // float2 math -> v_pk_*_f32; ds_read_b64/ds_write_b64; immediate offsets.
    if (tid < 38) {
        const float* ucol = u_s + 2 * tid;
        float*       wb   = xw_s + 2 * tid;   // w aliases xs (dead)
        float2 r0 = *(const float2*)(ucol + 0 * UST);
        float2 r1 = *(const float2*)(ucol + 1 * UST);
        float2 r2 = *(const float2*)(ucol + 2 * UST);
        float2 r3 = *(const float2*)(ucol + 3 * UST);
        float2 r4 = *(const float2*)(ucol + 4 * UST);
        float2 a0 = f2(0.f, 0.f), a1 = a0, a2 = a0, a3 = a0, a4 = a0, a5 = a0;
#pragma unroll
        for (int m = 0; m < 5; ++m) {     // prime (no store)
            float2 r5 = *(const float2*)(ucol + (m + 5) * UST);
            float2 z0 = pk_fma_s(fu[10], r0, pk_fma_s(fu[8], r1, pk_fma_s(fu[6], r2,
                        pk_fma_s(fu[4], r3, pk_fma_s(fu[2], r4, pk_mul_s(fu[0], r5))))));
            float2 z1 = pk_fma_s(fu[11], r0, pk_fma_s(fu[9], r1, pk_fma_s(fu[7], r2,
                        pk_fma_s(fu[5], r3, pk_fma_s(fu[3], r4, pk_mul_s(fu[1], r5))))));
            z0 = pk_lrelu(z0);
            z1 = pk_lrelu(z1);
            a0 = pk_fma_s(fd[1],  z1, pk_fma_s(fd[0],  z0, a0));
            a1 = pk_fma_s(fd[3],  z1, pk_fma_s(fd[2],  z0, a1));
            a2 = pk_fma_s(fd[5],  z1, pk_fma_s(fd[4],  z0, a2));
            a3 = pk_fma_s(fd[7],  z1, pk_fma_s(fd[6],  z0, a3));
            a4 = pk_fma_s(fd[9],  z1, pk_fma_s(fd[8],  z0, a4));
            a5 = pk_fma_s(fd[11], z1, pk_fma_s(fd[10], z0, a5));
            a5 = a4; a4 = a3; a3 = a2; a2 = a1; a1 = a0; a0 = f2(0.f, 0.f);
            r0 = r1; r1 = r2; r2 = r3; r3 = r4; r4 = r5;
        }
#pragma unroll
        for (int m = 5; m < 37; ++m) {    // steady (store one w row pair/iter)
            float2 r5 = *(const float2*)(ucol + (m + 5) * UST);
            float2 z0 = pk_fma_s(fu[10], r0, pk_fma_s(fu[8], r1, pk_fma_s(fu[6], r2,
                        pk_fma_s(fu[4], r3, pk_fma_s(fu[2], r4, pk_mul_s(fu[0], r5))))));
            float2 z1 = pk_fma_s(fu[11], r0, pk_fma_s(fu[9], r1, pk_fma_s(fu[7], r2,
                        pk_fma_s(fu[5], r3, pk_fma_s(fu[3], r4, pk_mul_s(fu[1], r5))))));
            z0 = pk_lrelu(z0);
            z1 = pk_lrelu(z1);
            a0 = pk_fma_s(fd[1],  z1, pk_fma_s(fd[0],  z0, a0));
            a1 = pk_fma_s(fd[3],  z1, pk_fma_s(fd[2],  z0, a1));
            a2 = pk_fma_s(fd[5],  z1, pk_fma_s(fd[4],  z0, a2));
            a3 = pk_fma_s(fd[7],  z1, pk_fma_s(fd[6],  z0, a3));
            a4 = pk_fma_s(fd[9],  z1, pk_fma_s(fd[8],  z0, a4));
            a5 = pk_fma_s(fd[11], z1, pk_fma_s(fd[10], z0, a5));
            *(float2*)(wb + (m - 5) * UST) = a5;
            a5 = a4; a4 = a3; a3 = a2; a2 = a1; a1 = a0; a0 = f2(0.f, 0.f);
            r0 = r1; r1 = r2; r2 = r3; r3 = r4; r4 = r5;
        }
    }
    __syncthreads();

    // ---- stage C: horizontal down-conv: w[32][76] -> out 32x32 ----
    // 256 tasks exactly: oy = tid>>3, g = tid&7; reads w[oy][8g..8g+17]
    {
        const float* w = xw_s;
        const int oy = tid >> 3;
        const int g  = tid & 7;
        const float* wr = w + oy * UST + 8 * g;
        float4 q0 = *(const float4*)&wr[0];
        float4 q1 = *(const float4*)&wr[4];
        float4 q2 = *(const float4*)&wr[8];
        float4 q3 = *(const float4*)&wr[12];
        float2 e  = *(const float2*)&wr[16];
        float o0v = fd[0]*q0.x + fd[1]*q0.y + fd[2]*q0.z + fd[3]*q0.w
                  + fd[4]*q1.x + fd[5]*q1.y + fd[6]*q1.z + fd[7]*q1.w
                  + fd[8]*q2.x + fd[9]*q2.y + fd[10]*q2.z + fd[11]*q2.w;
        float o1v = fd[0]*q0.z + fd[1]*q0.w + fd[2]*q1.x + fd[3]*q1.y
                  + fd[4]*q1.z + fd[5]*q1.w + fd[6]*q2.x + fd[7]*q2.y
                  + fd[8]*q2.z + fd[9]*q2.w + fd[10]*q3.x + fd[11]*q3.y;
        float o2v = fd[0]*q1.x + fd[1]*q1.y + fd[2]*q1.z + fd[3]*q1.w
                  + fd[4]*q2.x + fd[5]*q2.y + fd[6]*q2.z + fd[7]*q2.w
                  + fd[8]*q3.x + fd[9]*q3.y + fd[10]*q3.z + fd[11]*q3.w;
        float o3v = fd[0]*q1.z + fd[1]*q1.w + fd[2]*q2.x + fd[3]*q2.y
                  + fd[4]*q2.z + fd[5]*q2.w + fd[6]*q3.x + fd[7]*q3.y
                  + fd[8]*q3.z + fd[9]*q3.w + fd[10]*e.x  + fd[11]*e.y;
        float* __restrict__ outc = out + (size_t)ch * (128 * 128);
        *(float4*)(outc + (size_t)(oy0 + oy) * 128 + ox0 + 4 * g) =
            make_float4(o0v, o1v, o2v, o3v);
    }
}

extern "C" void kernel_launch(void* const* d_in, const int* in_sizes, int n_in,
                              void* d_out, int out_size, void* d_ws, size_t ws_size,
                              hipStream_t stream) {
    const float* x     = (const float*)d_in[0];
    const float* upf   = (const float*)d_in[1];
    const float* downf = (const float*)d_in[2];
    float* out = (float*)d_out;

    dim3 grid(128 / TOX, 128 / TOY, 8 * 128);   // 4 x 4 x 1024
    dim3 block(256);
    flrelu_fused_kernel<<<grid, block, 0, stream>>>(x, upf, downf, out);
}